// Round 2
// baseline (582.725 us; speedup 1.0000x reference)
//
#include <hip/hip_runtime.h>
#include <math.h>

// Problem constants (from reference setup_inputs)
#define B_   2
#define LA_  512
#define LB_  512
#define DH_  1024
#define P_   64
#define NCH_ 257           // 4*P + 1
#define EPS_ 1e-8f

typedef float v4f __attribute__((ext_vector_type(4)));

// ---------------------------------------------------------------------------
// Kernel 1: z = gelu_exact(h @ W + b), plus rn = 1/sqrt(sum(z^2) + EPS).
// One block per row (b*L + i), 256 threads.
//   TRANS=false: z stored [b, i, p]   (row-major, for z_a)
//   TRANS=true : z stored [b, p, i]   (transposed, for z_b -> coalesced j reads)
// ---------------------------------------------------------------------------
template <bool TRANS>
__global__ __launch_bounds__(256) void proj_gelu_kernel(
    const float* __restrict__ h,     // [B, L, DH]
    const float* __restrict__ W,     // [DH, P]
    const float* __restrict__ bias,  // [P]
    float* __restrict__ z,           // [B, L, P] or [B, P, L]
    float* __restrict__ rn,          // [B*L]
    int L)
{
    __shared__ float hs[DH_];
    __shared__ float partial[256];

    const int row = blockIdx.x;            // b*L + i
    const int b   = row >> 9;              // L == 512
    const int i   = row & (L - 1);
    const int tid = threadIdx.x;

    // Stage the h row (4 KB) into LDS, 256 threads x float4
    const float4* hrow4 = (const float4*)(h + (size_t)row * DH_);
    ((float4*)hs)[tid] = hrow4[tid];
    __syncthreads();

    // thread t computes quarter q of output channel p
    const int p = tid & 63;
    const int q = tid >> 6;                // 0..3
    const float* Wp = W + p;
    float acc = 0.f;
    const int k0 = q * 256;
    #pragma unroll 8
    for (int k = k0; k < k0 + 256; ++k)
        acc = fmaf(hs[k], Wp[k * P_], acc);
    partial[tid] = acc;
    __syncthreads();

    if (tid < 64) {
        float v = partial[tid] + partial[tid + 64] + partial[tid + 128] +
                  partial[tid + 192] + bias[tid];
        // exact GELU: 0.5*x*(1+erf(x/sqrt(2)))
        float g = 0.5f * v * (1.f + erff(v * 0.70710678118654752f));

        if (TRANS) z[((size_t)(b * P_ + tid)) * L + i] = g;
        else       z[(size_t)row * P_ + tid] = g;

        // wave-level reduce of g^2 over 64 lanes (tid<64 == wave 0)
        float s = g * g;
        #pragma unroll
        for (int off = 32; off > 0; off >>= 1)
            s += __shfl_down(s, off, 64);
        if (tid == 0)
            rn[row] = 1.f / sqrtf(s + EPS_);
    }
}

// ---------------------------------------------------------------------------
// Kernel 2: the 539 MB broadcast writer.
// One block per (b, i); 128 threads; thread t handles j = 4t..4t+3.
// Channels: [0,64) za  [64,128) zb  [128,192) |za-zb|  [192,256) za*zb  256 sim
// ---------------------------------------------------------------------------
__device__ __forceinline__ void nt_store4(float* p, float x, float y,
                                          float z, float w) {
    v4f v = {x, y, z, w};
    __builtin_nontemporal_store(v, (v4f*)p);
}

__global__ __launch_bounds__(128) void build_map_kernel(
    const float* __restrict__ za,    // [B, LA, P]
    const float* __restrict__ zbt,   // [B, P, LB]
    const float* __restrict__ rna,   // [B*LA]
    const float* __restrict__ rnb,   // [B*LB]
    float* __restrict__ out)         // [B, 257, LA, LB]
{
    __shared__ float zas[P_];

    const int idx = blockIdx.x;            // b*LA + i
    const int b   = idx >> 9;
    const int i   = idx & (LA_ - 1);
    const int tid = threadIdx.x;
    const int j0  = tid * 4;

    if (tid < P_) zas[tid] = za[(size_t)idx * P_ + tid];
    __syncthreads();

    const size_t CH = (size_t)LA_ * LB_;   // 262144 elements per channel plane
    float* ob = out + (size_t)b * NCH_ * CH + (size_t)i * LB_ + j0;
    const float* zbb = zbt + (size_t)b * P_ * LB_ + j0;

    float accx = 0.f, accy = 0.f, accz = 0.f, accw = 0.f;

    #pragma unroll 4
    for (int p = 0; p < P_; ++p) {
        const float a = zas[p];
        const v4f zb = *(const v4f*)(zbb + (size_t)p * LB_);

        const float prx = a * zb.x, pry = a * zb.y,
                    prz = a * zb.z, prw = a * zb.w;
        accx += prx; accy += pry; accz += prz; accw += prw;

        nt_store4(ob + (size_t)p * CH,         a, a, a, a);
        nt_store4(ob + (size_t)(64 + p) * CH,  zb.x, zb.y, zb.z, zb.w);
        nt_store4(ob + (size_t)(128 + p) * CH, fabsf(a - zb.x), fabsf(a - zb.y),
                                               fabsf(a - zb.z), fabsf(a - zb.w));
        nt_store4(ob + (size_t)(192 + p) * CH, prx, pry, prz, prw);
    }

    const float ra = rna[idx];
    const v4f rb = *(const v4f*)(rnb + b * LB_ + j0);
    nt_store4(ob + (size_t)256 * CH,
              accx * ra * rb.x, accy * ra * rb.y,
              accz * ra * rb.z, accw * ra * rb.w);
}

// ---------------------------------------------------------------------------
extern "C" void kernel_launch(void* const* d_in, const int* in_sizes, int n_in,
                              void* d_out, int out_size, void* d_ws, size_t ws_size,
                              hipStream_t stream)
{
    const float* h_a = (const float*)d_in[0];
    const float* h_b = (const float*)d_in[1];
    const float* Wa  = (const float*)d_in[2];
    const float* ba  = (const float*)d_in[3];
    const float* Wb  = (const float*)d_in[4];
    const float* bb  = (const float*)d_in[5];
    float* out = (float*)d_out;

    // workspace layout (floats): za[65536] | zbt[65536] | rna[1024] | rnb[1024]
    float* ws  = (float*)d_ws;
    float* za  = ws;
    float* zbt = ws + (size_t)B_ * LA_ * P_;
    float* rna = zbt + (size_t)B_ * P_ * LB_;
    float* rnb = rna + (size_t)B_ * LA_;

    proj_gelu_kernel<false><<<B_ * LA_, 256, 0, stream>>>(h_a, Wa, ba, za, rna, LA_);
    proj_gelu_kernel<true ><<<B_ * LB_, 256, 0, stream>>>(h_b, Wb, bb, zbt, rnb, LB_);
    build_map_kernel<<<B_ * LA_, 128, 0, stream>>>(za, zbt, rna, rnb, out);
}

// Round 3
// 570.395 us; speedup vs baseline: 1.0216x; 1.0216x over previous
//
#include <hip/hip_runtime.h>
#include <math.h>

// Problem constants (from reference setup_inputs)
#define B_    2
#define LA_   512
#define LB_   512
#define DH_   1024
#define P_    64
#define NCH_  257          // 4*P + 1
#define EPS_  1e-8f
#define CH_   ((size_t)LA_ * LB_)   // elements per channel plane (262144)
#define TILES_ 4
#define TROWS_ (LA_ / TILES_)       // 128 rows per writer block

// ---------------------------------------------------------------------------
// Kernel 1: z = gelu_exact(h @ W + b), stored TRANSPOSED [b, p, i];
// rn = 1/sqrt(sum_p z^2 + EPS). One block per row; blocks 0..1023 = side A,
// 1024..2047 = side B. 256 threads.
// ---------------------------------------------------------------------------
__global__ __launch_bounds__(256) void proj_gelu_kernel(
    const float* __restrict__ h_a, const float* __restrict__ Wa,
    const float* __restrict__ ba,
    const float* __restrict__ h_b, const float* __restrict__ Wb,
    const float* __restrict__ bb,
    float* __restrict__ zat,   // [B, P, LA]
    float* __restrict__ zbt,   // [B, P, LB]
    float* __restrict__ rna,   // [B*LA]
    float* __restrict__ rnb)   // [B*LB]
{
    __shared__ __align__(16) float hs[DH_];
    __shared__ float partial[256];

    const int side = blockIdx.x >> 10;      // 0 = A, 1 = B
    const int row  = blockIdx.x & 1023;     // b*512 + i
    const int b    = row >> 9;
    const int i    = row & 511;
    const int tid  = threadIdx.x;

    const float* h    = side ? h_b : h_a;
    const float* W    = side ? Wb  : Wa;
    const float* bias = side ? bb  : ba;
    float* z  = side ? zbt : zat;
    float* rn = side ? rnb : rna;

    // Stage the h row (4 KB) into LDS, 256 threads x float4
    ((float4*)hs)[tid] = ((const float4*)(h + (size_t)row * DH_))[tid];
    __syncthreads();

    // thread t computes quarter q of output channel p
    const int p = tid & 63;
    const int q = tid >> 6;                 // 0..3
    const float* Wp = W + p;
    float acc = 0.f;
    const int k0 = q * 256;
    #pragma unroll 8
    for (int k = k0; k < k0 + 256; ++k)
        acc = fmaf(hs[k], Wp[k * P_], acc);
    partial[tid] = acc;
    __syncthreads();

    if (tid < 64) {
        float v = partial[tid] + partial[tid + 64] + partial[tid + 128] +
                  partial[tid + 192] + bias[tid];
        // exact GELU: 0.5*x*(1+erf(x/sqrt(2)))
        float g = 0.5f * v * (1.f + erff(v * 0.70710678118654752f));

        z[((size_t)(b * P_ + tid)) * 512 + i] = g;   // transposed store

        float s = g * g;
        #pragma unroll
        for (int off = 32; off > 0; off >>= 1)
            s += __shfl_down(s, off, 64);
        if (tid == 0)
            rn[row] = 1.f / sqrtf(s + EPS_);
    }
}

// ---------------------------------------------------------------------------
// Kernel 2: broadcast-channel writer. One block per (channel, row-tile, b):
// writes a CONTIGUOUS 256 KB chunk of one plane (memset-shaped stream).
// ch in [0,256): t = ch>>6 selects {za, zb, |za-zb|, za*zb}, p = ch&63.
// 256 threads: tid -> (half = tid>>7, j = (tid&127)*4); per iteration the
// block writes rows 2it, 2it+1 back-to-back (4 KB contiguous).
// ---------------------------------------------------------------------------
__global__ __launch_bounds__(256) void writer_kernel(
    const float* __restrict__ zat,   // [B, P, LA]
    const float* __restrict__ zbt,   // [B, P, LB]
    float* __restrict__ out)         // [B, 257, LA, LB]
{
    __shared__ __align__(16) float zbrow[LB_];
    __shared__ __align__(16) float zacol[TROWS_];

    const int ch  = blockIdx.x;          // 0..255
    const int t   = ch >> 6;             // channel type
    const int p   = ch & 63;
    const int i0  = blockIdx.y * TROWS_;
    const int b   = blockIdx.z;
    const int tid = threadIdx.x;

    // stage: zbrow (512 floats) by threads 0..127, zacol (128 floats) by 128..159
    if (tid < 128)
        ((float4*)zbrow)[tid] = ((const float4*)(zbt + (size_t)(b * P_ + p) * 512))[tid];
    else if (tid < 160)
        ((float4*)zacol)[tid - 128] =
            ((const float4*)(zat + (size_t)(b * P_ + p) * 512 + i0))[tid - 128];
    __syncthreads();

    const int half = tid >> 7;           // 0 or 1 (row parity within pair)
    const int jj   = (tid & 127) * 4;
    const float4 zbv = *(const float4*)(zbrow + jj);

    float* op = out + (size_t)(b * NCH_ + ch) * CH_ + (size_t)(i0 + half) * LB_ + jj;

    if (t == 0) {                        // out[i][j] = za[i]
        #pragma unroll 4
        for (int it = 0; it < TROWS_ / 2; ++it) {
            const float a = zacol[2 * it + half];
            *(float4*)op = make_float4(a, a, a, a);
            op += 2 * LB_;
        }
    } else if (t == 1) {                 // out[i][j] = zb[j]
        #pragma unroll 4
        for (int it = 0; it < TROWS_ / 2; ++it) {
            *(float4*)op = make_float4(zbv.x, zbv.y, zbv.z, zbv.w);
            op += 2 * LB_;
        }
    } else if (t == 2) {                 // |za - zb|
        #pragma unroll 4
        for (int it = 0; it < TROWS_ / 2; ++it) {
            const float a = zacol[2 * it + half];
            *(float4*)op = make_float4(fabsf(a - zbv.x), fabsf(a - zbv.y),
                                       fabsf(a - zbv.z), fabsf(a - zbv.w));
            op += 2 * LB_;
        }
    } else {                             // za * zb
        #pragma unroll 4
        for (int it = 0; it < TROWS_ / 2; ++it) {
            const float a = zacol[2 * it + half];
            *(float4*)op = make_float4(a * zbv.x, a * zbv.y, a * zbv.z, a * zbv.w);
            op += 2 * LB_;
        }
    }
}

// ---------------------------------------------------------------------------
// Kernel 3: sim plane (channel 256): out[i][j] = dot(za_i, zb_j)*rna_i*rnb_j.
// Block = (row-tile of 16, b); 256 threads; thread covers j = tid, tid+256.
// ---------------------------------------------------------------------------
__global__ __launch_bounds__(256) void sim_kernel(
    const float* __restrict__ zat,   // [B, P, LA]
    const float* __restrict__ zbt,   // [B, P, LB]
    const float* __restrict__ rna,
    const float* __restrict__ rnb,
    float* __restrict__ out)
{
    __shared__ float zas[P_ * 16];       // [p][ii], 4 KB

    const int i0  = blockIdx.x * 16;
    const int b   = blockIdx.y;
    const int tid = threadIdx.x;

    // stage za tile: linear idx = tid*4 -> p = tid>>2, ii = (tid&3)*4
    {
        const int p  = tid >> 2;
        const int ii = (tid & 3) * 4;
        *(float4*)(zas + p * 16 + ii) =
            *(const float4*)(zat + (size_t)(b * P_ + p) * 512 + i0 + ii);
    }
    __syncthreads();

    float acc0[16], acc1[16];
    #pragma unroll
    for (int ii = 0; ii < 16; ++ii) { acc0[ii] = 0.f; acc1[ii] = 0.f; }

    for (int p = 0; p < P_; ++p) {
        const float zb0 = zbt[(size_t)(b * P_ + p) * 512 + tid];
        const float zb1 = zbt[(size_t)(b * P_ + p) * 512 + tid + 256];
        #pragma unroll
        for (int ii = 0; ii < 16; ++ii) {
            const float a = zas[p * 16 + ii];
            acc0[ii] = fmaf(a, zb0, acc0[ii]);
            acc1[ii] = fmaf(a, zb1, acc1[ii]);
        }
    }

    const float rb0 = rnb[b * 512 + tid];
    const float rb1 = rnb[b * 512 + tid + 256];
    float* plane = out + (size_t)(b * NCH_ + 256) * CH_;
    #pragma unroll
    for (int ii = 0; ii < 16; ++ii) {
        const float ra = rna[b * 512 + i0 + ii];
        plane[(size_t)(i0 + ii) * LB_ + tid]       = acc0[ii] * ra * rb0;
        plane[(size_t)(i0 + ii) * LB_ + tid + 256] = acc1[ii] * ra * rb1;
    }
}

// ---------------------------------------------------------------------------
extern "C" void kernel_launch(void* const* d_in, const int* in_sizes, int n_in,
                              void* d_out, int out_size, void* d_ws, size_t ws_size,
                              hipStream_t stream)
{
    const float* h_a = (const float*)d_in[0];
    const float* h_b = (const float*)d_in[1];
    const float* Wa  = (const float*)d_in[2];
    const float* ba  = (const float*)d_in[3];
    const float* Wb  = (const float*)d_in[4];
    const float* bb  = (const float*)d_in[5];
    float* out = (float*)d_out;

    // workspace (floats): zat[65536] | zbt[65536] | rna[1024] | rnb[1024]
    float* ws  = (float*)d_ws;
    float* zat = ws;
    float* zbt = zat + (size_t)B_ * P_ * LA_;
    float* rna = zbt + (size_t)B_ * P_ * LB_;
    float* rnb = rna + (size_t)B_ * LA_;

    proj_gelu_kernel<<<2 * B_ * LA_, 256, 0, stream>>>(
        h_a, Wa, ba, h_b, Wb, bb, zat, zbt, rna, rnb);
    writer_kernel<<<dim3(256, TILES_, B_), 256, 0, stream>>>(zat, zbt, out);
    sim_kernel<<<dim3(LA_ / 16, B_), 256, 0, stream>>>(zat, zbt, rna, rnb, out);
}